// Round 1
// baseline (615.300 us; speedup 1.0000x reference)
//
#include <hip/hip_runtime.h>
#include <math.h>

#define HID 64
#define BN_EPS 1e-5f
#define NBMAX 256

typedef unsigned int uint;
typedef unsigned short ushort;

// ============ bf16 helpers ============

__device__ inline uint bf16pk(float a, float b) {
    uint ua = __builtin_bit_cast(uint, a);
    ua += 0x7fff + ((ua >> 16) & 1);
    uint ub = __builtin_bit_cast(uint, b);
    ub += 0x7fff + ((ub >> 16) & 1);
    return (ua >> 16) | (ub & 0xffff0000u);
}
__device__ inline float bfl(uint v) { return __builtin_bit_cast(float, v << 16); }
__device__ inline float bfh(uint v) { return __builtin_bit_cast(float, v & 0xffff0000u); }

// ============ fused hist + scan (last-block pattern) ============
// edges packed to 32-bit ((dst&255)<<16 | src) — requires N < 65536 (N=50000 here).

__global__ __launch_bounds__(256) void k_hist_scan(const int* __restrict__ ei, int E, int NB, int N,
                                                   int* __restrict__ bcnt_d, int* __restrict__ bcnt_s,
                                                   int* __restrict__ done,
                                                   int* __restrict__ bbase_d, int* __restrict__ cursor_d,
                                                   int* __restrict__ bbase_s, int* __restrict__ cursor_s,
                                                   int* __restrict__ rowptr) {
    __shared__ int hd[256], hs[256];
    __shared__ int lastFlag;
    int t = threadIdx.x;
    hd[t] = 0; hs[t] = 0;
    __syncthreads();
    for (int e = blockIdx.x * 256 + t; e < E; e += gridDim.x * 256) {
        int src = ei[e], dst = ei[E + e];
        atomicAdd(&hs[src >> 8], 1);
        atomicAdd(&hd[dst >> 8], 1);
    }
    __syncthreads();
    if (t < NB) {
        if (hd[t]) atomicAdd(&bcnt_d[t], hd[t]);
        if (hs[t]) atomicAdd(&bcnt_s[t], hs[t]);
    }
    __threadfence();
    __syncthreads();
    if (t == 0) lastFlag = (atomicAdd(done, 1) == (int)gridDim.x - 1);
    __syncthreads();
    if (!lastFlag) return;
    // last block: coherent reads via atomic RMW, then double scan (reuse hd/hs as scan buffers)
    int v = (t < NB) ? atomicAdd(&bcnt_d[t], 0) : 0;
    hd[t] = v; __syncthreads();
    for (int s = 1; s < 256; s <<= 1) { int u = (t >= s) ? hd[t - s] : 0; __syncthreads(); hd[t] += u; __syncthreads(); }
    int excl = hd[t] - v;
    if (t <= NB) bbase_d[t] = excl;
    if (t < NB) cursor_d[t] = excl;
    if (t == 0) rowptr[N] = E;
    __syncthreads();
    v = (t < NB) ? atomicAdd(&bcnt_s[t], 0) : 0;
    hs[t] = v; __syncthreads();
    for (int s = 1; s < 256; s <<= 1) { int u = (t >= s) ? hs[t - s] : 0; __syncthreads(); hs[t] += u; __syncthreads(); }
    excl = hs[t] - v;
    if (t <= NB) bbase_s[t] = excl;
    if (t < NB) cursor_s[t] = excl;
}

// fused: blocks [0,SCB) scatter edges into buckets; blocks [SCB,SCB+SB) do BN-stats
// stage-1 over x, now reduced straight into stats[0..255] via device atomics.
__global__ __launch_bounds__(256) void k_scatter_stats(const int* __restrict__ ei, int E, int NB, int SCB,
                                                       int* __restrict__ cursor_d, int* __restrict__ cursor_s,
                                                       uint* __restrict__ bedge, int* __restrict__ bsrc,
                                                       const float* __restrict__ X, int n,
                                                       float* __restrict__ stats) {
    __shared__ __align__(16) char smemraw[8192];
    int t = threadIdx.x;
    if ((int)blockIdx.x < SCB) {
        int* hd = (int*)smemraw;            // 256
        int* hs = hd + 256;                 // 256
        int* curd = hs + 256;               // 256
        int* curs = curd + 256;             // 256 -> 4KB total
        int chunk = (E + SCB - 1) / SCB;
        int e0 = blockIdx.x * chunk;
        int e1 = min(e0 + chunk, E);
        if (t < NB) { hd[t] = 0; hs[t] = 0; }
        __syncthreads();
        for (int e = e0 + t; e < e1; e += 256) {
            int src = ei[e], dst = ei[E + e];
            atomicAdd(&hd[dst >> 8], 1);
            atomicAdd(&hs[src >> 8], 1);
        }
        __syncthreads();
        if (t < NB) {
            curd[t] = hd[t] ? atomicAdd(&cursor_d[t], hd[t]) : 0;
            curs[t] = hs[t] ? atomicAdd(&cursor_s[t], hs[t]) : 0;
        }
        __syncthreads();
        for (int e = e0 + t; e < e1; e += 256) {
            int src = ei[e], dst = ei[E + e];
            int pd = atomicAdd(&curd[dst >> 8], 1);
            bedge[pd] = ((uint)(dst & 255) << 16) | (uint)src;   // N < 65536
            int ps = atomicAdd(&curs[src >> 8], 1);
            bsrc[ps] = src;
        }
    } else {
        // BN stats stage-1 over x [n,128] -> atomicAdd into stats[0..127]=sum, [128..255]=sumsq
        int b = blockIdx.x - SCB;
        int SB = gridDim.x - SCB;
        float4* shs = (float4*)smemraw;     // 256 float4 = 4KB
        float4* shq = shs + 256;            // 4KB more
        int c4 = t & 31, rsub = t >> 5;
        float4 s = make_float4(0.f, 0.f, 0.f, 0.f);
        float4 q = make_float4(0.f, 0.f, 0.f, 0.f);
        for (int r = b * 8 + rsub; r < n; r += SB * 8) {
            float4 v = ((const float4*)X)[(size_t)r * 32 + c4];
            s.x += v.x; s.y += v.y; s.z += v.z; s.w += v.w;
            q.x = fmaf(v.x, v.x, q.x); q.y = fmaf(v.y, v.y, q.y);
            q.z = fmaf(v.z, v.z, q.z); q.w = fmaf(v.w, v.w, q.w);
        }
        shs[t] = s; shq[t] = q;
        __syncthreads();
        if (rsub == 0) {
            #pragma unroll
            for (int k = 1; k < 8; k++) {
                float4 a = shs[t + k * 32], bq = shq[t + k * 32];
                s.x += a.x; s.y += a.y; s.z += a.z; s.w += a.w;
                q.x += bq.x; q.y += bq.y; q.z += bq.z; q.w += bq.w;
            }
            atomicAdd(&stats[4 * t + 0], s.x); atomicAdd(&stats[4 * t + 1], s.y);
            atomicAdd(&stats[4 * t + 2], s.z); atomicAdd(&stats[4 * t + 3], s.w);
            atomicAdd(&stats[128 + 4 * t + 0], q.x); atomicAdd(&stats[128 + 4 * t + 1], q.y);
            atomicAdd(&stats[128 + 4 * t + 2], q.z); atomicAdd(&stats[128 + 4 * t + 3], q.w);
        }
    }
}

// fused: blocks [0,NB) dst-CSR; [NB,2NB) outdeg->dis
__global__ __launch_bounds__(256) void k_build_csr_outdeg(
        const uint* __restrict__ bedge, const int* __restrict__ bbase_d,
        const int* __restrict__ bsrc, const int* __restrict__ bbase_s,
        int N, int NB,
        int* __restrict__ rowptr, int* __restrict__ eidx, float* __restrict__ dis) {
    __shared__ int h[256], off[256], cur[256];
    int t = threadIdx.x, b = blockIdx.x;
    if (b < NB) {
        int base = bbase_d[b], end = bbase_d[b + 1];
        h[t] = 0; __syncthreads();
        for (int p = base + t; p < end; p += 256)
            atomicAdd(&h[(int)(bedge[p] >> 16) & 255], 1);
        __syncthreads();
        off[t] = h[t]; __syncthreads();
        for (int s = 1; s < 256; s <<= 1) { int u = (t >= s) ? off[t - s] : 0; __syncthreads(); off[t] += u; __syncthreads(); }
        int excl = off[t] - h[t];
        int node = (b << 8) + t;
        if (node <= N) rowptr[node] = base + excl;
        cur[t] = excl; __syncthreads();
        for (int p = base + t; p < end; p += 256) {
            uint be = bedge[p];
            int bin = (int)(be >> 16) & 255;
            int pos = atomicAdd(&cur[bin], 1);
            eidx[base + pos] = (int)(be & 0xffffu);
        }
    } else {
        int b2 = b - NB;
        int base = bbase_s[b2], end = bbase_s[b2 + 1];
        h[t] = 0; __syncthreads();
        for (int p = base + t; p < end; p += 256) atomicAdd(&h[bsrc[p] & 255], 1);
        __syncthreads();
        int node = (b2 << 8) + t;
        if (node < N) dis[node] = rsqrtf((float)(h[t] + 1));
    }
}

// ============ GEMM with fused BN-fold prologue + optional atomic-stats epilogue ============

template <int K, bool RELU, bool DIS, bool STATS, bool HASB>
__global__ __launch_bounds__(256) void k_gemm(const float* __restrict__ X, const float* __restrict__ W,
                                              const float* __restrict__ stats,
                                              const float* __restrict__ gamma, const float* __restrict__ beta,
                                              const float* __restrict__ bias0, const float* __restrict__ dis,
                                              float n_inv, void* __restrict__ out, int n,
                                              float* __restrict__ sout) {
    constexpr int KC = 64;
    constexpr int XS = 68;
    __shared__ float Xs[KC * XS];
    __shared__ float Wsm[KC * HID];
    __shared__ float As[128], Cs[128];

    int t = threadIdx.x;
    int tx = t & 15, ty = t >> 4;
    int row0 = blockIdx.x * 64;

    if (t < K) {
        float mu = stats[t] * n_inv;
        float var = stats[K + t] * n_inv - mu * mu;
        float a = gamma[t] * rsqrtf(var + BN_EPS);
        As[t] = a;
        Cs[t] = beta[t] - mu * a;
    }
    __syncthreads();

    float acc[4][4];
    #pragma unroll
    for (int i = 0; i < 4; i++)
        #pragma unroll
        for (int j = 0; j < 4; j++) acc[i][j] = 0.f;
    float4 bp = make_float4(0.f, 0.f, 0.f, 0.f);

    for (int kc = 0; kc < K; kc += KC) {
        #pragma unroll
        for (int it = 0; it < 4; ++it) {
            int id = t + 256 * it;
            int r = id >> 4, c4 = id & 15;
            float4 v = make_float4(0.f, 0.f, 0.f, 0.f);
            if (row0 + r < n) v = *(const float4*)(X + (size_t)(row0 + r) * K + kc + 4 * c4);
            int kk = 4 * c4;
            Xs[(kk + 0) * XS + r] = v.x;
            Xs[(kk + 1) * XS + r] = v.y;
            Xs[(kk + 2) * XS + r] = v.z;
            Xs[(kk + 3) * XS + r] = v.w;
        }
        {
            const float4* wsrc = (const float4*)(W + (size_t)kc * HID);
            #pragma unroll
            for (int it = 0; it < 4; ++it) {
                int id = t + 256 * it;
                int kl = id >> 4;
                float4 raw = wsrc[id];
                float a = As[kc + kl], c = Cs[kc + kl];
                float4 sc;
                sc.x = a * raw.x; sc.y = a * raw.y; sc.z = a * raw.z; sc.w = a * raw.w;
                ((float4*)Wsm)[id] = sc;
                bp.x = fmaf(c, raw.x, bp.x);
                bp.y = fmaf(c, raw.y, bp.y);
                bp.z = fmaf(c, raw.z, bp.z);
                bp.w = fmaf(c, raw.w, bp.w);
            }
        }
        __syncthreads();
        #pragma unroll 8
        for (int k = 0; k < KC; ++k) {
            float4 xv = *(const float4*)&Xs[k * XS + 4 * ty];
            float4 wv = *(const float4*)&Wsm[k * HID + 4 * tx];
            acc[0][0] = fmaf(xv.x, wv.x, acc[0][0]);
            acc[0][1] = fmaf(xv.x, wv.y, acc[0][1]);
            acc[0][2] = fmaf(xv.x, wv.z, acc[0][2]);
            acc[0][3] = fmaf(xv.x, wv.w, acc[0][3]);
            acc[1][0] = fmaf(xv.y, wv.x, acc[1][0]);
            acc[1][1] = fmaf(xv.y, wv.y, acc[1][1]);
            acc[1][2] = fmaf(xv.y, wv.z, acc[1][2]);
            acc[1][3] = fmaf(xv.y, wv.w, acc[1][3]);
            acc[2][0] = fmaf(xv.z, wv.x, acc[2][0]);
            acc[2][1] = fmaf(xv.z, wv.y, acc[2][1]);
            acc[2][2] = fmaf(xv.z, wv.z, acc[2][2]);
            acc[2][3] = fmaf(xv.z, wv.w, acc[2][3]);
            acc[3][0] = fmaf(xv.w, wv.x, acc[3][0]);
            acc[3][1] = fmaf(xv.w, wv.y, acc[3][1]);
            acc[3][2] = fmaf(xv.w, wv.z, acc[3][2]);
            acc[3][3] = fmaf(xv.w, wv.w, acc[3][3]);
        }
        __syncthreads();
    }

    {
        float* redb = Xs + 2048;
        *(float4*)&redb[ty * 64 + 4 * tx] = bp;
        __syncthreads();
        if (t < 64) {
            float s = 0.f;
            #pragma unroll
            for (int k = 0; k < 16; ++k) s += redb[k * 64 + t];
            Xs[3072 + t] = s + (HASB ? bias0[t] : 0.f);
        }
        __syncthreads();
    }
    float4 bv = *(const float4*)&Xs[3072 + 4 * tx];

    float4 cs = make_float4(0.f, 0.f, 0.f, 0.f);
    float4 cq = make_float4(0.f, 0.f, 0.f, 0.f);
    #pragma unroll
    for (int i = 0; i < 4; ++i) {
        int row = row0 + 4 * ty + i;
        bool valid = row < n;
        float vx = acc[i][0] + bv.x, vy = acc[i][1] + bv.y;
        float vz = acc[i][2] + bv.z, vw = acc[i][3] + bv.w;
        if constexpr (DIS) {
            if (valid) {
                float d = dis[row];
                uint2 pk;
                pk.x = bf16pk(vx * d, vy * d);
                pk.y = bf16pk(vz * d, vw * d);
                *(uint2*)((ushort*)out + (size_t)row * HID + 4 * tx) = pk;
            }
        } else {
            float4 v;
            v.x = RELU ? fmaxf(vx, 0.f) : vx;
            v.y = RELU ? fmaxf(vy, 0.f) : vy;
            v.z = RELU ? fmaxf(vz, 0.f) : vz;
            v.w = RELU ? fmaxf(vw, 0.f) : vw;
            if (valid) {
                *(float4*)((float*)out + (size_t)row * HID + 4 * tx) = v;
                if constexpr (STATS) {
                    cs.x += v.x; cs.y += v.y; cs.z += v.z; cs.w += v.w;
                    cq.x = fmaf(v.x, v.x, cq.x); cq.y = fmaf(v.y, v.y, cq.y);
                    cq.z = fmaf(v.z, v.z, cq.z); cq.w = fmaf(v.w, v.w, cq.w);
                }
            }
        }
    }
    if constexpr (STATS) {
        __syncthreads();
        float* reds = Xs;
        float* redq = Xs + 1024;
        *(float4*)&reds[ty * 64 + 4 * tx] = cs;
        *(float4*)&redq[ty * 64 + 4 * tx] = cq;
        __syncthreads();
        if (t < 64) {
            float s = 0.f, q = 0.f;
            #pragma unroll
            for (int k = 0; k < 16; ++k) { s += reds[k * 64 + t]; q += redq[k * 64 + t]; }
            atomicAdd(&sout[t], s);
            atomicAdd(&sout[64 + t], q);
        }
    }
}

// ============ aggregation: 8 nodes/block, per node 4 edge-slots x 8 feature-lanes,
// 16B uint4 gathers, 2x unroll (8 edges in flight), shfl-xor slot reduce.
// !POOL: writes fp32 out rows + atomicAdd BN stats. POOL: fuses global_add_pool. ============

template <bool POOL>
__global__ __launch_bounds__(256) void k_agg(const ushort* __restrict__ s, const int* __restrict__ rowptr,
                                             const int* __restrict__ eidx, const float* __restrict__ dis,
                                             const float* __restrict__ bias, float* __restrict__ out, int n,
                                             float* __restrict__ sout, const int* __restrict__ batch,
                                             float* __restrict__ pool_out) {
    __shared__ float shs[8 * 64];
    __shared__ float shq[8 * 64];
    __shared__ int ib[8];
    int t = threadIdx.x;
    int nl = t >> 5;          // node slot in block (0..7); 2 nodes per wave
    int li = t & 31;
    int slot = li >> 3;       // edge slot 0..3
    int c = li & 7;           // uint4 column -> features 8c..8c+7
    int i = blockIdx.x * 8 + nl;
    const uint4* sp4 = (const uint4*)s;
    float a[8];
    #pragma unroll
    for (int k = 0; k < 8; ++k) a[k] = 0.f;
    bool valid = i < n;
    if (valid) {
        int q = rowptr[i] + slot;
        int qe = rowptr[i + 1];
        while (q + 4 < qe) {
            int j0 = eidx[q], j1 = eidx[q + 4];
            uint4 v0 = sp4[(size_t)j0 * 8 + c];
            uint4 v1 = sp4[(size_t)j1 * 8 + c];
            q += 8;
            a[0] += bfl(v0.x) + bfl(v1.x); a[1] += bfh(v0.x) + bfh(v1.x);
            a[2] += bfl(v0.y) + bfl(v1.y); a[3] += bfh(v0.y) + bfh(v1.y);
            a[4] += bfl(v0.z) + bfl(v1.z); a[5] += bfh(v0.z) + bfh(v1.z);
            a[6] += bfl(v0.w) + bfl(v1.w); a[7] += bfh(v0.w) + bfh(v1.w);
        }
        if (q < qe) {
            int j0 = eidx[q];
            uint4 v0 = sp4[(size_t)j0 * 8 + c];
            a[0] += bfl(v0.x); a[1] += bfh(v0.x);
            a[2] += bfl(v0.y); a[3] += bfh(v0.y);
            a[4] += bfl(v0.z); a[5] += bfh(v0.z);
            a[6] += bfl(v0.w); a[7] += bfh(v0.w);
        }
    }
    // reduce across the 4 edge slots (lanes differ in bits 3,4 -> stays within node group)
    #pragma unroll
    for (int k = 0; k < 8; ++k) a[k] += __shfl_xor(a[k], 8);
    #pragma unroll
    for (int k = 0; k < 8; ++k) a[k] += __shfl_xor(a[k], 16);

    if (li < 8) {
        float r[8];
        if (valid) {
            uint4 v = sp4[(size_t)i * 8 + c];   // self-loop contribution
            a[0] += bfl(v.x); a[1] += bfh(v.x);
            a[2] += bfl(v.y); a[3] += bfh(v.y);
            a[4] += bfl(v.z); a[5] += bfh(v.z);
            a[6] += bfl(v.w); a[7] += bfh(v.w);
            float d = dis[i];
            float4 b0 = *(const float4*)(bias + 8 * c);
            float4 b1 = *(const float4*)(bias + 8 * c + 4);
            r[0] = fmaxf(fmaf(d, a[0], b0.x), 0.f);
            r[1] = fmaxf(fmaf(d, a[1], b0.y), 0.f);
            r[2] = fmaxf(fmaf(d, a[2], b0.z), 0.f);
            r[3] = fmaxf(fmaf(d, a[3], b0.w), 0.f);
            r[4] = fmaxf(fmaf(d, a[4], b1.x), 0.f);
            r[5] = fmaxf(fmaf(d, a[5], b1.y), 0.f);
            r[6] = fmaxf(fmaf(d, a[6], b1.z), 0.f);
            r[7] = fmaxf(fmaf(d, a[7], b1.w), 0.f);
            if constexpr (!POOL) {
                *(float4*)(out + (size_t)i * HID + 8 * c)     = make_float4(r[0], r[1], r[2], r[3]);
                *(float4*)(out + (size_t)i * HID + 8 * c + 4) = make_float4(r[4], r[5], r[6], r[7]);
            }
        } else {
            #pragma unroll
            for (int k = 0; k < 8; ++k) r[k] = 0.f;
        }
        #pragma unroll
        for (int k = 0; k < 8; ++k) shs[nl * 64 + 8 * c + k] = r[k];
        if constexpr (!POOL) {
            #pragma unroll
            for (int k = 0; k < 8; ++k) shq[nl * 64 + 8 * c + k] = r[k] * r[k];
        }
    }
    if constexpr (POOL) {
        if (li == 0) ib[nl] = valid ? batch[i] : -1;
    }
    __syncthreads();
    if (t < 64) {
        if constexpr (!POOL) {
            float ss = 0.f, qq = 0.f;
            #pragma unroll
            for (int k = 0; k < 8; ++k) { ss += shs[k * 64 + t]; qq += shq[k * 64 + t]; }
            atomicAdd(&sout[t], ss);
            atomicAdd(&sout[64 + t], qq);
        } else {
            // batch is sorted -> run-length merge across the 8 nodes, then few atomics
            int g = ib[0];
            float run = shs[t];
            #pragma unroll
            for (int k = 1; k < 8; ++k) {
                int gk = ib[k];
                float v = shs[k * 64 + t];
                if (gk == g) {
                    run += v;
                } else {
                    if (g >= 0) atomicAdd(&pool_out[(size_t)g * HID + t], run);
                    g = gk; run = v;
                }
            }
            if (g >= 0) atomicAdd(&pool_out[(size_t)g * HID + t], run);
        }
    }
}

// ============ driver ============

extern "C" void kernel_launch(void* const* d_in, const int* in_sizes, int n_in,
                              void* d_out, int out_size, void* d_ws, size_t ws_size,
                              hipStream_t stream) {
    const float* x     = (const float*)d_in[0];
    const int*   ei    = (const int*)d_in[1];
    const int*   batch = (const int*)d_in[2];
    const float* bnfg  = (const float*)d_in[3];
    const float* bnfb  = (const float*)d_in[4];
    const float* Wfeat = (const float*)d_in[5];
    const float* bfeat = (const float*)d_in[6];
    const float* bng   = (const float*)d_in[7];
    const float* bnb   = (const float*)d_in[8];
    const float* Ws    = (const float*)d_in[9];
    const float* bs    = (const float*)d_in[10];
    float* out = (float*)d_out;

    const int N   = in_sizes[2];
    const int E   = in_sizes[1] / 2;
    const int L   = in_sizes[9] / (HID * HID);
    const int NB  = (N + 255) >> 8;
    const int SCB = 256;                    // scatter blocks
    const int SB  = 512;                    // stats<128> stage-1 blocks
    const int gG  = (N + 63) / 64;          // gemm blocks
    const int gA  = (N + 7) / 8;            // agg blocks
    const float n_inv = 1.f / (float)N;

    char* w = (char*)d_ws;
    auto alloc = [&](size_t bytes) { char* p = w; w += (bytes + 255) & ~(size_t)255; return p; };
    // ---- zeroed prefix ----
    int*   bcnt_d = (int*)alloc(256 * 4);
    int*   bcnt_s = (int*)alloc(256 * 4);
    int*   done   = (int*)alloc(256);
    // stats layout: [0..255] x-stats (sum128,sq128); then per-stage 64-feature
    // slots of 128 floats at 256 + 128*l  (l=0: gemm128 out; l=1: agg0 out; l=2: agg1 out)
    float* stats  = (float*)alloc(1024 * 4);
    size_t zero_bytes = (size_t)(w - (char*)d_ws);
    // ---- rest ----
    int*   bbase_d  = (int*)alloc(257 * 4);
    int*   cursor_d = (int*)alloc(256 * 4);
    int*   bbase_s  = (int*)alloc(257 * 4);
    int*   cursor_s = (int*)alloc(256 * 4);
    int*   rowptr   = (int*)alloc(((size_t)N + 1) * 4);
    int*   eidx     = (int*)alloc((size_t)E * 4);
    float* dis      = (float*)alloc((size_t)N * 4);
    float* bufA     = (float*)alloc((size_t)N * HID * 4);
    ushort* bufB    = (ushort*)alloc((size_t)N * HID * 2);
    uint* bedge = (uint*)bufA;     // E*4 <= N*HID*4 ; consumed before bufA first written
    int*  bsrc  = (int*)bufB;      // E*4 <= N*HID*2 ; consumed before bufB first written

    hipMemsetAsync(d_ws, 0, zero_bytes, stream);
    hipMemsetAsync(d_out, 0, (size_t)out_size * sizeof(float), stream);  // pool accumulates atomically

    // graph build (hist + scan fused via last-block pattern; stats over x overlapped)
    k_hist_scan<<<512, 256, 0, stream>>>(ei, E, NB, N, bcnt_d, bcnt_s, done,
                                         bbase_d, cursor_d, bbase_s, cursor_s, rowptr);
    k_scatter_stats<<<SCB + SB, 256, 0, stream>>>(ei, E, NB, SCB, cursor_d, cursor_s,
                                                  bedge, bsrc, x, N, stats);
    k_build_csr_outdeg<<<2 * NB, 256, 0, stream>>>(bedge, bbase_d, bsrc, bbase_s, N, NB,
                                                   rowptr, eidx, dis);

    // feature layer: gemm<128> (BN fold fused; stats-of-output -> atomic slot 0)
    k_gemm<128, true, false, true, true><<<gG, 256, 0, stream>>>(
        x, Wfeat, stats, bnfg, bnfb, bfeat, nullptr, n_inv, (void*)bufA, N, stats + 256);

    // GCN layers
    for (int l = 0; l < L; ++l) {
        k_gemm<64, false, true, false, false><<<gG, 256, 0, stream>>>(
            bufA, Ws + (size_t)l * HID * HID, stats + 256 + 128 * l,
            bng + (size_t)l * HID, bnb + (size_t)l * HID,
            nullptr, dis, n_inv, (void*)bufB, N, nullptr);
        if (l < L - 1) {
            k_agg<false><<<gA, 256, 0, stream>>>(bufB, rowptr, eidx, dis, bs + (size_t)l * HID,
                                                 bufA, N, stats + 256 + 128 * (l + 1), nullptr, nullptr);
        } else {
            k_agg<true><<<gA, 256, 0, stream>>>(bufB, rowptr, eidx, dis, bs + (size_t)l * HID,
                                                nullptr, N, nullptr, batch, out);
        }
    }
}

// Round 2
// 287.894 us; speedup vs baseline: 2.1372x; 2.1372x over previous
//
#include <hip/hip_runtime.h>
#include <math.h>

#define HID 64
#define BN_EPS 1e-5f
#define NBMAX 256
#define NREP 64   // stats replica slots (contention: nblocks/NREP per address)

typedef unsigned int uint;
typedef unsigned short ushort;

// ============ bf16 helpers ============

__device__ inline uint bf16pk(float a, float b) {
    uint ua = __builtin_bit_cast(uint, a);
    ua += 0x7fff + ((ua >> 16) & 1);
    uint ub = __builtin_bit_cast(uint, b);
    ub += 0x7fff + ((ub >> 16) & 1);
    return (ua >> 16) | (ub & 0xffff0000u);
}
__device__ inline float bfl(uint v) { return __builtin_bit_cast(float, v << 16); }
__device__ inline float bfh(uint v) { return __builtin_bit_cast(float, v & 0xffff0000u); }

// ============ fused hist + scan (last-block pattern) ============
// edges packed to 32-bit ((dst&255)<<16 | src) — requires N < 65536 (N=50000 here).

__global__ __launch_bounds__(256) void k_hist_scan(const int* __restrict__ ei, int E, int NB, int N,
                                                   int* __restrict__ bcnt_d, int* __restrict__ bcnt_s,
                                                   int* __restrict__ done,
                                                   int* __restrict__ bbase_d, int* __restrict__ cursor_d,
                                                   int* __restrict__ bbase_s, int* __restrict__ cursor_s,
                                                   int* __restrict__ rowptr) {
    __shared__ int hd[256], hs[256];
    __shared__ int lastFlag;
    int t = threadIdx.x;
    hd[t] = 0; hs[t] = 0;
    __syncthreads();
    for (int e = blockIdx.x * 256 + t; e < E; e += gridDim.x * 256) {
        int src = ei[e], dst = ei[E + e];
        atomicAdd(&hs[src >> 8], 1);
        atomicAdd(&hd[dst >> 8], 1);
    }
    __syncthreads();
    if (t < NB) {
        if (hd[t]) atomicAdd(&bcnt_d[t], hd[t]);
        if (hs[t]) atomicAdd(&bcnt_s[t], hs[t]);
    }
    __threadfence();
    __syncthreads();
    if (t == 0) lastFlag = (atomicAdd(done, 1) == (int)gridDim.x - 1);
    __syncthreads();
    if (!lastFlag) return;
    // last block: coherent reads via atomic RMW, then double scan (reuse hd/hs as scan buffers)
    int v = (t < NB) ? atomicAdd(&bcnt_d[t], 0) : 0;
    hd[t] = v; __syncthreads();
    for (int s = 1; s < 256; s <<= 1) { int u = (t >= s) ? hd[t - s] : 0; __syncthreads(); hd[t] += u; __syncthreads(); }
    int excl = hd[t] - v;
    if (t <= NB) bbase_d[t] = excl;
    if (t < NB) cursor_d[t] = excl;
    if (t == 0) rowptr[N] = E;
    __syncthreads();
    v = (t < NB) ? atomicAdd(&bcnt_s[t], 0) : 0;
    hs[t] = v; __syncthreads();
    for (int s = 1; s < 256; s <<= 1) { int u = (t >= s) ? hs[t - s] : 0; __syncthreads(); hs[t] += u; __syncthreads(); }
    excl = hs[t] - v;
    if (t <= NB) bbase_s[t] = excl;
    if (t < NB) cursor_s[t] = excl;
}

// fused: blocks [0,SCB) scatter edges into buckets; blocks [SCB,SCB+SB) do BN-stats
// stage-1 over x, reduced into replica slots of statsX (64 replicas x 256 floats).
__global__ __launch_bounds__(256) void k_scatter_stats(const int* __restrict__ ei, int E, int NB, int SCB,
                                                       int* __restrict__ cursor_d, int* __restrict__ cursor_s,
                                                       uint* __restrict__ bedge, int* __restrict__ bsrc,
                                                       const float* __restrict__ X, int n,
                                                       float* __restrict__ stats) {
    __shared__ __align__(16) char smemraw[8192];
    int t = threadIdx.x;
    if ((int)blockIdx.x < SCB) {
        int* hd = (int*)smemraw;            // 256
        int* hs = hd + 256;                 // 256
        int* curd = hs + 256;               // 256
        int* curs = curd + 256;             // 256 -> 4KB total
        int chunk = (E + SCB - 1) / SCB;
        int e0 = blockIdx.x * chunk;
        int e1 = min(e0 + chunk, E);
        if (t < NB) { hd[t] = 0; hs[t] = 0; }
        __syncthreads();
        for (int e = e0 + t; e < e1; e += 256) {
            int src = ei[e], dst = ei[E + e];
            atomicAdd(&hd[dst >> 8], 1);
            atomicAdd(&hs[src >> 8], 1);
        }
        __syncthreads();
        if (t < NB) {
            curd[t] = hd[t] ? atomicAdd(&cursor_d[t], hd[t]) : 0;
            curs[t] = hs[t] ? atomicAdd(&cursor_s[t], hs[t]) : 0;
        }
        __syncthreads();
        for (int e = e0 + t; e < e1; e += 256) {
            int src = ei[e], dst = ei[E + e];
            int pd = atomicAdd(&curd[dst >> 8], 1);
            bedge[pd] = ((uint)(dst & 255) << 16) | (uint)src;   // N < 65536
            int ps = atomicAdd(&curs[src >> 8], 1);
            bsrc[ps] = src;
        }
    } else {
        // BN stats stage-1 over x [n,128] -> replica slot (bid & 63): [0..127]=sum, [128..255]=sumsq
        int b = blockIdx.x - SCB;
        int SB = gridDim.x - SCB;
        float4* shs = (float4*)smemraw;     // 256 float4 = 4KB
        float4* shq = shs + 256;            // 4KB more
        int c4 = t & 31, rsub = t >> 5;
        float4 s = make_float4(0.f, 0.f, 0.f, 0.f);
        float4 q = make_float4(0.f, 0.f, 0.f, 0.f);
        for (int r = b * 8 + rsub; r < n; r += SB * 8) {
            float4 v = ((const float4*)X)[(size_t)r * 32 + c4];
            s.x += v.x; s.y += v.y; s.z += v.z; s.w += v.w;
            q.x = fmaf(v.x, v.x, q.x); q.y = fmaf(v.y, v.y, q.y);
            q.z = fmaf(v.z, v.z, q.z); q.w = fmaf(v.w, v.w, q.w);
        }
        shs[t] = s; shq[t] = q;
        __syncthreads();
        if (rsub == 0) {
            #pragma unroll
            for (int k = 1; k < 8; k++) {
                float4 a = shs[t + k * 32], bq = shq[t + k * 32];
                s.x += a.x; s.y += a.y; s.z += a.z; s.w += a.w;
                q.x += bq.x; q.y += bq.y; q.z += bq.z; q.w += bq.w;
            }
            float* sb = stats + ((int)blockIdx.x & (NREP - 1)) * 256;
            atomicAdd(&sb[4 * t + 0], s.x); atomicAdd(&sb[4 * t + 1], s.y);
            atomicAdd(&sb[4 * t + 2], s.z); atomicAdd(&sb[4 * t + 3], s.w);
            atomicAdd(&sb[128 + 4 * t + 0], q.x); atomicAdd(&sb[128 + 4 * t + 1], q.y);
            atomicAdd(&sb[128 + 4 * t + 2], q.z); atomicAdd(&sb[128 + 4 * t + 3], q.w);
        }
    }
}

// fused: blocks [0,NB) dst-CSR; [NB,2NB) outdeg->dis
__global__ __launch_bounds__(256) void k_build_csr_outdeg(
        const uint* __restrict__ bedge, const int* __restrict__ bbase_d,
        const int* __restrict__ bsrc, const int* __restrict__ bbase_s,
        int N, int NB,
        int* __restrict__ rowptr, int* __restrict__ eidx, float* __restrict__ dis) {
    __shared__ int h[256], off[256], cur[256];
    int t = threadIdx.x, b = blockIdx.x;
    if (b < NB) {
        int base = bbase_d[b], end = bbase_d[b + 1];
        h[t] = 0; __syncthreads();
        for (int p = base + t; p < end; p += 256)
            atomicAdd(&h[(int)(bedge[p] >> 16) & 255], 1);
        __syncthreads();
        off[t] = h[t]; __syncthreads();
        for (int s = 1; s < 256; s <<= 1) { int u = (t >= s) ? off[t - s] : 0; __syncthreads(); off[t] += u; __syncthreads(); }
        int excl = off[t] - h[t];
        int node = (b << 8) + t;
        if (node <= N) rowptr[node] = base + excl;
        cur[t] = excl; __syncthreads();
        for (int p = base + t; p < end; p += 256) {
            uint be = bedge[p];
            int bin = (int)(be >> 16) & 255;
            int pos = atomicAdd(&cur[bin], 1);
            eidx[base + pos] = (int)(be & 0xffffu);
        }
    } else {
        int b2 = b - NB;
        int base = bbase_s[b2], end = bbase_s[b2 + 1];
        h[t] = 0; __syncthreads();
        for (int p = base + t; p < end; p += 256) atomicAdd(&h[bsrc[p] & 255], 1);
        __syncthreads();
        int node = (b2 << 8) + t;
        if (node < N) dis[node] = rsqrtf((float)(h[t] + 1));
    }
}

// ============ GEMM with fused BN-fold prologue (replica-summed stats)
//              + optional replica-atomic stats epilogue ============

template <int K, bool RELU, bool DIS, bool STATS, bool HASB>
__global__ __launch_bounds__(256) void k_gemm(const float* __restrict__ X, const float* __restrict__ W,
                                              const float* __restrict__ stats,
                                              const float* __restrict__ gamma, const float* __restrict__ beta,
                                              const float* __restrict__ bias0, const float* __restrict__ dis,
                                              float n_inv, void* __restrict__ out, int n,
                                              float* __restrict__ sout) {
    constexpr int KC = 64;
    constexpr int XS = 68;
    __shared__ float Xs[KC * XS];
    __shared__ float Wsm[KC * HID];
    __shared__ float As[128], Cs[128];

    int t = threadIdx.x;
    int tx = t & 15, ty = t >> 4;
    int row0 = blockIdx.x * 64;

    if (t < K) {
        // sum the NREP replica slots (L2-hot; stride 2K floats per replica)
        float ssum = 0.f, qsum = 0.f;
        const float* sp = stats + t;
        #pragma unroll 8
        for (int r = 0; r < NREP; ++r) {
            ssum += sp[(size_t)r * 2 * K];
            qsum += sp[(size_t)r * 2 * K + K];
        }
        float mu = ssum * n_inv;
        float var = qsum * n_inv - mu * mu;
        float a = gamma[t] * rsqrtf(var + BN_EPS);
        As[t] = a;
        Cs[t] = beta[t] - mu * a;
    }
    __syncthreads();

    float acc[4][4];
    #pragma unroll
    for (int i = 0; i < 4; i++)
        #pragma unroll
        for (int j = 0; j < 4; j++) acc[i][j] = 0.f;
    float4 bp = make_float4(0.f, 0.f, 0.f, 0.f);

    for (int kc = 0; kc < K; kc += KC) {
        #pragma unroll
        for (int it = 0; it < 4; ++it) {
            int id = t + 256 * it;
            int r = id >> 4, c4 = id & 15;
            float4 v = make_float4(0.f, 0.f, 0.f, 0.f);
            if (row0 + r < n) v = *(const float4*)(X + (size_t)(row0 + r) * K + kc + 4 * c4);
            int kk = 4 * c4;
            Xs[(kk + 0) * XS + r] = v.x;
            Xs[(kk + 1) * XS + r] = v.y;
            Xs[(kk + 2) * XS + r] = v.z;
            Xs[(kk + 3) * XS + r] = v.w;
        }
        {
            const float4* wsrc = (const float4*)(W + (size_t)kc * HID);
            #pragma unroll
            for (int it = 0; it < 4; ++it) {
                int id = t + 256 * it;
                int kl = id >> 4;
                float4 raw = wsrc[id];
                float a = As[kc + kl], c = Cs[kc + kl];
                float4 sc;
                sc.x = a * raw.x; sc.y = a * raw.y; sc.z = a * raw.z; sc.w = a * raw.w;
                ((float4*)Wsm)[id] = sc;
                bp.x = fmaf(c, raw.x, bp.x);
                bp.y = fmaf(c, raw.y, bp.y);
                bp.z = fmaf(c, raw.z, bp.z);
                bp.w = fmaf(c, raw.w, bp.w);
            }
        }
        __syncthreads();
        #pragma unroll 8
        for (int k = 0; k < KC; ++k) {
            float4 xv = *(const float4*)&Xs[k * XS + 4 * ty];
            float4 wv = *(const float4*)&Wsm[k * HID + 4 * tx];
            acc[0][0] = fmaf(xv.x, wv.x, acc[0][0]);
            acc[0][1] = fmaf(xv.x, wv.y, acc[0][1]);
            acc[0][2] = fmaf(xv.x, wv.z, acc[0][2]);
            acc[0][3] = fmaf(xv.x, wv.w, acc[0][3]);
            acc[1][0] = fmaf(xv.y, wv.x, acc[1][0]);
            acc[1][1] = fmaf(xv.y, wv.y, acc[1][1]);
            acc[1][2] = fmaf(xv.y, wv.z, acc[1][2]);
            acc[1][3] = fmaf(xv.y, wv.w, acc[1][3]);
            acc[2][0] = fmaf(xv.z, wv.x, acc[2][0]);
            acc[2][1] = fmaf(xv.z, wv.y, acc[2][1]);
            acc[2][2] = fmaf(xv.z, wv.z, acc[2][2]);
            acc[2][3] = fmaf(xv.z, wv.w, acc[2][3]);
            acc[3][0] = fmaf(xv.w, wv.x, acc[3][0]);
            acc[3][1] = fmaf(xv.w, wv.y, acc[3][1]);
            acc[3][2] = fmaf(xv.w, wv.z, acc[3][2]);
            acc[3][3] = fmaf(xv.w, wv.w, acc[3][3]);
        }
        __syncthreads();
    }

    {
        float* redb = Xs + 2048;
        *(float4*)&redb[ty * 64 + 4 * tx] = bp;
        __syncthreads();
        if (t < 64) {
            float s = 0.f;
            #pragma unroll
            for (int k = 0; k < 16; ++k) s += redb[k * 64 + t];
            Xs[3072 + t] = s + (HASB ? bias0[t] : 0.f);
        }
        __syncthreads();
    }
    float4 bv = *(const float4*)&Xs[3072 + 4 * tx];

    float4 cs = make_float4(0.f, 0.f, 0.f, 0.f);
    float4 cq = make_float4(0.f, 0.f, 0.f, 0.f);
    #pragma unroll
    for (int i = 0; i < 4; ++i) {
        int row = row0 + 4 * ty + i;
        bool valid = row < n;
        float vx = acc[i][0] + bv.x, vy = acc[i][1] + bv.y;
        float vz = acc[i][2] + bv.z, vw = acc[i][3] + bv.w;
        if constexpr (DIS) {
            if (valid) {
                float d = dis[row];
                uint2 pk;
                pk.x = bf16pk(vx * d, vy * d);
                pk.y = bf16pk(vz * d, vw * d);
                *(uint2*)((ushort*)out + (size_t)row * HID + 4 * tx) = pk;
            }
        } else {
            float4 v;
            v.x = RELU ? fmaxf(vx, 0.f) : vx;
            v.y = RELU ? fmaxf(vy, 0.f) : vy;
            v.z = RELU ? fmaxf(vz, 0.f) : vz;
            v.w = RELU ? fmaxf(vw, 0.f) : vw;
            if (valid) {
                *(float4*)((float*)out + (size_t)row * HID + 4 * tx) = v;
                if constexpr (STATS) {
                    cs.x += v.x; cs.y += v.y; cs.z += v.z; cs.w += v.w;
                    cq.x = fmaf(v.x, v.x, cq.x); cq.y = fmaf(v.y, v.y, cq.y);
                    cq.z = fmaf(v.z, v.z, cq.z); cq.w = fmaf(v.w, v.w, cq.w);
                }
            }
        }
    }
    if constexpr (STATS) {
        __syncthreads();
        float* reds = Xs;
        float* redq = Xs + 1024;
        *(float4*)&reds[ty * 64 + 4 * tx] = cs;
        *(float4*)&redq[ty * 64 + 4 * tx] = cq;
        __syncthreads();
        if (t < 64) {
            float s = 0.f, q = 0.f;
            #pragma unroll
            for (int k = 0; k < 16; ++k) { s += reds[k * 64 + t]; q += redq[k * 64 + t]; }
            float* sb = sout + ((int)blockIdx.x & (NREP - 1)) * 128;
            atomicAdd(&sb[t], s);
            atomicAdd(&sb[64 + t], q);
        }
    }
}

// ============ aggregation: 8 nodes/block, per node 4 edge-slots x 8 feature-lanes,
// 16B uint4 gathers, branch-free batches of 4 edges per slot (4 gathers in flight
// per lane; masked lanes gather the cache-hot self row with weight 0).
// !POOL: writes fp32 out rows + replica-atomic BN stats. POOL: fuses global_add_pool. ============

template <bool POOL>
__global__ __launch_bounds__(256) void k_agg(const ushort* __restrict__ s, const int* __restrict__ rowptr,
                                             const int* __restrict__ eidx, const float* __restrict__ dis,
                                             const float* __restrict__ bias, float* __restrict__ out, int n,
                                             float* __restrict__ sout, const int* __restrict__ batch,
                                             float* __restrict__ pool_out) {
    __shared__ float shs[8 * 64];
    __shared__ float shq[8 * 64];
    __shared__ int ib[8];
    int t = threadIdx.x;
    int nl = t >> 5;          // node slot in block (0..7); 2 nodes per wave
    int li = t & 31;
    int slot = li >> 3;       // edge slot 0..3
    int c = li & 7;           // uint4 column -> features 8c..8c+7
    int i = blockIdx.x * 8 + nl;
    const uint4* sp4 = (const uint4*)s;
    float a[8];
    #pragma unroll
    for (int k = 0; k < 8; ++k) a[k] = 0.f;
    bool valid = i < n;
    if (valid) {
        int qe = rowptr[i + 1];
        int q = rowptr[i] + slot;
        while (q < qe) {
            // branch-free batch of 4 edges for this slot (stride 4 between slots)
            int qm = qe - 1;
            int q1 = q + 4, q2 = q + 8, q3 = q + 12;
            bool p1 = q1 < qe, p2 = q2 < qe, p3 = q3 < qe;
            int j0 = eidx[q];
            int j1 = eidx[min(q1, qm)];
            int j2 = eidx[min(q2, qm)];
            int j3 = eidx[min(q3, qm)];
            if (!p1) j1 = i;           // masked -> self row (L1-hot), weight 0
            if (!p2) j2 = i;
            if (!p3) j3 = i;
            uint4 v0 = sp4[(size_t)j0 * 8 + c];
            uint4 v1 = sp4[(size_t)j1 * 8 + c];
            uint4 v2 = sp4[(size_t)j2 * 8 + c];
            uint4 v3 = sp4[(size_t)j3 * 8 + c];
            float m1 = p1 ? 1.f : 0.f;
            float m2 = p2 ? 1.f : 0.f;
            float m3 = p3 ? 1.f : 0.f;
            q += 16;
            a[0] += bfl(v0.x); a[1] += bfh(v0.x);
            a[2] += bfl(v0.y); a[3] += bfh(v0.y);
            a[4] += bfl(v0.z); a[5] += bfh(v0.z);
            a[6] += bfl(v0.w); a[7] += bfh(v0.w);
            a[0] = fmaf(m1, bfl(v1.x), a[0]); a[1] = fmaf(m1, bfh(v1.x), a[1]);
            a[2] = fmaf(m1, bfl(v1.y), a[2]); a[3] = fmaf(m1, bfh(v1.y), a[3]);
            a[4] = fmaf(m1, bfl(v1.z), a[4]); a[5] = fmaf(m1, bfh(v1.z), a[5]);
            a[6] = fmaf(m1, bfl(v1.w), a[6]); a[7] = fmaf(m1, bfh(v1.w), a[7]);
            a[0] = fmaf(m2, bfl(v2.x), a[0]); a[1] = fmaf(m2, bfh(v2.x), a[1]);
            a[2] = fmaf(m2, bfl(v2.y), a[2]); a[3] = fmaf(m2, bfh(v2.y), a[3]);
            a[4] = fmaf(m2, bfl(v2.z), a[4]); a[5] = fmaf(m2, bfh(v2.z), a[5]);
            a[6] = fmaf(m2, bfl(v2.w), a[6]); a[7] = fmaf(m2, bfh(v2.w), a[7]);
            a[0] = fmaf(m3, bfl(v3.x), a[0]); a[1] = fmaf(m3, bfh(v3.x), a[1]);
            a[2] = fmaf(m3, bfl(v3.y), a[2]); a[3] = fmaf(m3, bfh(v3.y), a[3]);
            a[4] = fmaf(m3, bfl(v3.z), a[4]); a[5] = fmaf(m3, bfh(v3.z), a[5]);
            a[6] = fmaf(m3, bfl(v3.w), a[6]); a[7] = fmaf(m3, bfh(v3.w), a[7]);
        }
    }
    // reduce across the 4 edge slots (lanes differ in bits 3,4 -> stays within node group)
    #pragma unroll
    for (int k = 0; k < 8; ++k) a[k] += __shfl_xor(a[k], 8);
    #pragma unroll
    for (int k = 0; k < 8; ++k) a[k] += __shfl_xor(a[k], 16);

    if (li < 8) {
        float r[8];
        if (valid) {
            uint4 v = sp4[(size_t)i * 8 + c];   // self-loop contribution
            a[0] += bfl(v.x); a[1] += bfh(v.x);
            a[2] += bfl(v.y); a[3] += bfh(v.y);
            a[4] += bfl(v.z); a[5] += bfh(v.z);
            a[6] += bfl(v.w); a[7] += bfh(v.w);
            float d = dis[i];
            float4 b0 = *(const float4*)(bias + 8 * c);
            float4 b1 = *(const float4*)(bias + 8 * c + 4);
            r[0] = fmaxf(fmaf(d, a[0], b0.x), 0.f);
            r[1] = fmaxf(fmaf(d, a[1], b0.y), 0.f);
            r[2] = fmaxf(fmaf(d, a[2], b0.z), 0.f);
            r[3] = fmaxf(fmaf(d, a[3], b0.w), 0.f);
            r[4] = fmaxf(fmaf(d, a[4], b1.x), 0.f);
            r[5] = fmaxf(fmaf(d, a[5], b1.y), 0.f);
            r[6] = fmaxf(fmaf(d, a[6], b1.z), 0.f);
            r[7] = fmaxf(fmaf(d, a[7], b1.w), 0.f);
            if constexpr (!POOL) {
                *(float4*)(out + (size_t)i * HID + 8 * c)     = make_float4(r[0], r[1], r[2], r[3]);
                *(float4*)(out + (size_t)i * HID + 8 * c + 4) = make_float4(r[4], r[5], r[6], r[7]);
            }
        } else {
            #pragma unroll
            for (int k = 0; k < 8; ++k) r[k] = 0.f;
        }
        #pragma unroll
        for (int k = 0; k < 8; ++k) shs[nl * 64 + 8 * c + k] = r[k];
        if constexpr (!POOL) {
            #pragma unroll
            for (int k = 0; k < 8; ++k) shq[nl * 64 + 8 * c + k] = r[k] * r[k];
        }
    }
    if constexpr (POOL) {
        if (li == 0) ib[nl] = valid ? batch[i] : -1;
    }
    __syncthreads();
    if (t < 64) {
        if constexpr (!POOL) {
            float ss = 0.f, qq = 0.f;
            #pragma unroll
            for (int k = 0; k < 8; ++k) { ss += shs[k * 64 + t]; qq += shq[k * 64 + t]; }
            float* sb = sout + ((int)blockIdx.x & (NREP - 1)) * 128;
            atomicAdd(&sb[t], ss);
            atomicAdd(&sb[64 + t], qq);
        } else {
            // batch is sorted -> run-length merge across the 8 nodes, then few atomics
            int g = ib[0];
            float run = shs[t];
            #pragma unroll
            for (int k = 1; k < 8; ++k) {
                int gk = ib[k];
                float v = shs[k * 64 + t];
                if (gk == g) {
                    run += v;
                } else {
                    if (g >= 0) atomicAdd(&pool_out[(size_t)g * HID + t], run);
                    g = gk; run = v;
                }
            }
            if (g >= 0) atomicAdd(&pool_out[(size_t)g * HID + t], run);
        }
    }
}

// ============ driver ============

extern "C" void kernel_launch(void* const* d_in, const int* in_sizes, int n_in,
                              void* d_out, int out_size, void* d_ws, size_t ws_size,
                              hipStream_t stream) {
    const float* x     = (const float*)d_in[0];
    const int*   ei    = (const int*)d_in[1];
    const int*   batch = (const int*)d_in[2];
    const float* bnfg  = (const float*)d_in[3];
    const float* bnfb  = (const float*)d_in[4];
    const float* Wfeat = (const float*)d_in[5];
    const float* bfeat = (const float*)d_in[6];
    const float* bng   = (const float*)d_in[7];
    const float* bnb   = (const float*)d_in[8];
    const float* Ws    = (const float*)d_in[9];
    const float* bs    = (const float*)d_in[10];
    float* out = (float*)d_out;

    const int N   = in_sizes[2];
    const int E   = in_sizes[1] / 2;
    const int L   = in_sizes[9] / (HID * HID);
    const int NB  = (N + 255) >> 8;
    const int SCB = 256;                    // scatter blocks
    const int SB  = 512;                    // stats<128> stage-1 blocks
    const int gG  = (N + 63) / 64;          // gemm blocks
    const int gA  = (N + 7) / 8;            // agg blocks
    const float n_inv = 1.f / (float)N;

    char* w = (char*)d_ws;
    auto alloc = [&](size_t bytes) { char* p = w; w += (bytes + 255) & ~(size_t)255; return p; };
    // ---- zeroed prefix ----
    int*   bcnt_d = (int*)alloc(256 * 4);
    int*   bcnt_s = (int*)alloc(256 * 4);
    int*   done   = (int*)alloc(256);
    // statsX: NREP replicas x (sum128, sq128) for the x BN
    float* statsX = (float*)alloc((size_t)NREP * 256 * 4);
    // statsL: 3 layer slots, each NREP replicas x (sum64, sq64)
    float* statsL = (float*)alloc((size_t)3 * NREP * 128 * 4);
    size_t zero_bytes = (size_t)(w - (char*)d_ws);
    // ---- rest ----
    int*   bbase_d  = (int*)alloc(257 * 4);
    int*   cursor_d = (int*)alloc(256 * 4);
    int*   bbase_s  = (int*)alloc(257 * 4);
    int*   cursor_s = (int*)alloc(256 * 4);
    int*   rowptr   = (int*)alloc(((size_t)N + 1) * 4);
    int*   eidx     = (int*)alloc((size_t)E * 4);
    float* dis      = (float*)alloc((size_t)N * 4);
    float* bufA     = (float*)alloc((size_t)N * HID * 4);
    ushort* bufB    = (ushort*)alloc((size_t)N * HID * 2);
    uint* bedge = (uint*)bufA;     // E*4 <= N*HID*4 ; consumed before bufA first written
    int*  bsrc  = (int*)bufB;      // E*4 <= N*HID*2 ; consumed before bufB first written

    hipMemsetAsync(d_ws, 0, zero_bytes, stream);
    hipMemsetAsync(d_out, 0, (size_t)out_size * sizeof(float), stream);  // pool accumulates atomically

    // graph build (hist + scan fused via last-block pattern; stats over x overlapped)
    k_hist_scan<<<512, 256, 0, stream>>>(ei, E, NB, N, bcnt_d, bcnt_s, done,
                                         bbase_d, cursor_d, bbase_s, cursor_s, rowptr);
    k_scatter_stats<<<SCB + SB, 256, 0, stream>>>(ei, E, NB, SCB, cursor_d, cursor_s,
                                                  bedge, bsrc, x, N, statsX);
    k_build_csr_outdeg<<<2 * NB, 256, 0, stream>>>(bedge, bbase_d, bsrc, bbase_s, N, NB,
                                                   rowptr, eidx, dis);

    // feature layer: gemm<128> (BN fold fused; stats-of-output -> replica slot 0)
    k_gemm<128, true, false, true, true><<<gG, 256, 0, stream>>>(
        x, Wfeat, statsX, bnfg, bnfb, bfeat, nullptr, n_inv, (void*)bufA, N, statsL);

    // GCN layers
    for (int l = 0; l < L; ++l) {
        k_gemm<64, false, true, false, false><<<gG, 256, 0, stream>>>(
            bufA, Ws + (size_t)l * HID * HID, statsL + (size_t)l * NREP * 128,
            bng + (size_t)l * HID, bnb + (size_t)l * HID,
            nullptr, dis, n_inv, (void*)bufB, N, nullptr);
        if (l < L - 1) {
            k_agg<false><<<gA, 256, 0, stream>>>(bufB, rowptr, eidx, dis, bs + (size_t)l * HID,
                                                 bufA, N, statsL + (size_t)(l + 1) * NREP * 128,
                                                 nullptr, nullptr);
        } else {
            k_agg<true><<<gA, 256, 0, stream>>>(bufB, rowptr, eidx, dis, bs + (size_t)l * HID,
                                                nullptr, N, nullptr, batch, out);
        }
    }
}